// Round 4
// baseline (128.286 us; speedup 1.0000x reference)
//
#include <hip/hip_runtime.h>
#include <math.h>

#define IR_LEN  2000
#define PFRAME  80
#define NFRAMES 300
#define NBATCH  2
#define NROWS   (NBATCH*NFRAMES)     // 600
#define T_TOTAL (NFRAMES*PFRAME)     // 24000
#define NCOEF   25
#define NHALF   2049                 // half spectrum f = 0..2048
#define TWO_PI  6.283185307179586f

// ---------------------------------------------------------------------------
// A0: E[row][f] = exp(C[row][f]),  C[f] = sum_k c[k] e^{-2pi i f k/4096}
// ---------------------------------------------------------------------------
__global__ __launch_bounds__(256) void exp_spec_kernel(
        const float* __restrict__ mc, float2* __restrict__ E) {
    const int idx = blockIdx.x * 256 + threadIdx.x;
    if (idx >= NROWS * NHALF) return;
    const int row = idx / NHALF;
    const int f   = idx - row * NHALF;
    const float* c = mc + row * NCOEF;

    const float ang = -(TWO_PI / 4096.0f) * (float)f;
    float ws, wc; sincosf(ang, &ws, &wc);      // e^{-2pi i f/4096}
    float cr = 1.0f, ci = 0.0f, Cr = 0.0f, Ci = 0.0f;
    #pragma unroll
    for (int k = 0; k < NCOEF; k++) {
        const float cc = c[k];
        Cr += cc * cr; Ci += cc * ci;
        const float nr = cr * wc - ci * ws;
        const float ni = cr * ws + ci * wc;
        cr = nr; ci = ni;
    }
    const float m = expf(Cr);
    float si, co; sincosf(Ci, &si, &co);
    E[idx] = make_float2(m * co, m * si);
}

// ---------------------------------------------------------------------------
// A1: 4096-pt IFFT (real part, first 2000), 64x64 factorization, 2 blocks/row
// (d-halves).  f = 64a + b, n = 64c + d, this block owns d in [32q, 32q+32).
// Stage 1: thread = (b-octet t&7, d = t>>3): 8b x 1d tile, 32 acc FMA + 4 rot
// FMA per a-step; folded half read b128-aligned with in-register reversal.
// Stage 2: thread = (2 d's = 2*(t&15), cg = t>>4): c in {cg, cg+16}, second c
// via i^b sign patterns (no extra multiplies), float2 G reads (2-way = free).
// ---------------------------------------------------------------------------
__global__ __launch_bounds__(256, 4) void ifft_kernel(
        const float2* __restrict__ E, float* __restrict__ h_out) {
    __shared__ __align__(16) float  EHr[2052], EHi[2052];  // 16.4 KB
    __shared__ __align__(16) float2 GI[32 * 65];           // 16.6 KB

    const int row = blockIdx.x >> 1;
    const int q   = blockIdx.x & 1;
    const int t   = threadIdx.x;

    const float2* Erow = E + row * NHALF;
    for (int i = t; i < NHALF; i += 256) {
        const float2 e = Erow[i];
        EHr[i] = e.x; EHi[i] = e.y;
    }
    __syncthreads();

    // ---------------- Stage 1 ----------------
    {
        const int b0 = (t & 7) * 8;
        const int dl = t >> 3;                 // 0..31
        const int d  = q * 32 + dl;
        float ar[8] = {0,0,0,0,0,0,0,0}, ai[8] = {0,0,0,0,0,0,0,0};
        float wi_, wr_; sincosf((TWO_PI / 64.0f) * (float)d, &wi_, &wr_);
        const float wr = wr_, wi = wi_;
        float rr = 1.0f, ri = 0.0f;

        #pragma unroll 8
        for (int a = 0; a < 32; a++) {
            const float4 r0 = *(const float4*)&EHr[a * 64 + b0];
            const float4 r1 = *(const float4*)&EHr[a * 64 + b0 + 4];
            const float4 i0 = *(const float4*)&EHi[a * 64 + b0];
            const float4 i1 = *(const float4*)&EHi[a * 64 + b0 + 4];
            const float er[8] = {r0.x,r0.y,r0.z,r0.w,r1.x,r1.y,r1.z,r1.w};
            const float ei[8] = {i0.x,i0.y,i0.z,i0.w,i1.x,i1.y,i1.z,i1.w};
            #pragma unroll
            for (int i = 0; i < 8; i++) {
                ar[i] += er[i] * rr - ei[i] * ri;
                ai[i] += er[i] * ri + ei[i] * rr;
            }
            const float nr = rr * wr - ri * wi;
            const float ni = rr * wi + ri * wr;
            rr = nr; ri = ni;
        }
        #pragma unroll 8
        for (int a = 32; a < 64; a++) {
            const int base = (64 - a) * 64 - b0;   // mult of 8, in [8, 2048]
            const float  rs = EHr[base];
            const float4 rA = *(const float4*)&EHr[base - 4];
            const float4 rB = *(const float4*)&EHr[base - 8];
            const float  is = EHi[base];
            const float4 iA = *(const float4*)&EHi[base - 4];
            const float4 iB = *(const float4*)&EHi[base - 8];
            const float er[8] = {rs, rA.w, rA.z, rA.y, rA.x, rB.w, rB.z, rB.y};
            const float em[8] = {is, iA.w, iA.z, iA.y, iA.x, iB.w, iB.z, iB.y};
            #pragma unroll
            for (int i = 0; i < 8; i++) {
                // true imag = -em:  ar += er*rr + em*ri ; ai += er*ri - em*rr
                ar[i] += er[i] * rr + em[i] * ri;
                ai[i] += er[i] * ri - em[i] * rr;
            }
            const float nr = rr * wr - ri * wi;
            const float ni = rr * wi + ri * wr;
            rr = nr; ri = ni;
        }
        // twiddle-correct G' = G * e^{2pi i b d/4096} via rotation over b
        float ps_, pc_; sincosf((TWO_PI / 4096.0f) * (float)d, &ps_, &pc_);
        float cs_, cc_; sincosf((TWO_PI / 4096.0f) * (float)(b0 * d), &cs_, &cc_);
        float cr = cc_, ci = cs_;
        #pragma unroll
        for (int i = 0; i < 8; i++) {
            const float gr = ar[i] * cr - ai[i] * ci;
            const float gi = ar[i] * ci + ai[i] * cr;
            GI[dl * 65 + b0 + i] = make_float2(gr, gi);
            const float nr = cr * pc_ - ci * ps_;
            const float ni = cr * ps_ + ci * pc_;
            cr = nr; ci = ni;
        }
    }
    __syncthreads();

    // ---------------- Stage 2 ----------------
    {
        const int dp = (t & 15) * 2;           // local d pair
        const int cg = t >> 4;                 // 0..15 ; second c = cg + 16
        float swi_, swr_; sincosf((TWO_PI / 64.0f) * (float)cg, &swi_, &swr_);
        const float swr = swr_, swi = swi_;    // step e^{2pi i cg/64}
        float rr = 1.0f, ri = 0.0f;
        float a0c0 = 0, a1c0 = 0, a0c1 = 0, a1c1 = 0;

        #pragma unroll 4
        for (int bb = 0; bb < 64; bb += 4) {
            #pragma unroll
            for (int m = 0; m < 4; m++) {
                const int b = bb + m;
                const float2 g0 = GI[dp * 65 + b];
                const float2 g1 = GI[(dp + 1) * 65 + b];
                a0c0 += g0.x * rr - g0.y * ri;
                a1c0 += g1.x * rr - g1.y * ri;
                float tr, ti;
                if      (m == 0) { tr = rr;  ti = ri;  }
                else if (m == 1) { tr = -ri; ti = rr;  }
                else if (m == 2) { tr = -rr; ti = -ri; }
                else             { tr = ri;  ti = -rr; }
                a0c1 += g0.x * tr - g0.y * ti;
                a1c1 += g1.x * tr - g1.y * ti;
                const float nr = rr * swr - ri * swi;
                const float ni = rr * swi + ri * swr;
                rr = nr; ri = ni;
            }
        }

        const float sc = 1.0f / 4096.0f;
        float* ho = h_out + row * IR_LEN;
        const int dg = q * 32 + dp;
        const int n00 = 64 * cg + dg;              // <= 1023, always valid
        ho[n00]     = a0c0 * sc;
        ho[n00 + 1] = a1c0 * sc;
        const int n10 = 64 * (cg + 16) + dg;       // up to 2047
        if (n10 < IR_LEN)     ho[n10]     = a0c1 * sc;
        if (n10 + 1 < IR_LEN) ho[n10 + 1] = a1c1 * sc;
    }
}

// ---------------------------------------------------------------------------
// B: time-varying FIR. Block per (batch, frame). Thread = (og = t%10 -> 8
// outputs, kc = t/10 -> 80-tap chunk). Sliding 12-float x window: per 4-tap
// step 3x b128 LDS for 64 FMA. Partials to LDS slabs, tree-free reduction.
// ---------------------------------------------------------------------------
__global__ __launch_bounds__(256) void fir_kernel(
        const float* __restrict__ x, const float* __restrict__ h,
        float* __restrict__ y) {
    __shared__ __align__(16) float h0[IR_LEN], h1[IR_LEN];   // 16 KB
    __shared__ __align__(16) float xw[2080];                 // 8.3 KB
    __shared__ __align__(16) float red0[2000], red1[2000];   // 16 KB (25 x 80)

    const int row   = blockIdx.x;              // 0..599
    const int batch = row / NFRAMES;
    const int frame = row - batch * NFRAMES;
    const int t0    = frame * PFRAME;
    const int t     = threadIdx.x;
    const int row1  = (frame + 1 < NFRAMES) ? row + 1 : row;

    const float4* hp0 = (const float4*)(h + (size_t)row  * IR_LEN);
    const float4* hp1 = (const float4*)(h + (size_t)row1 * IR_LEN);
    for (int i = t; i < IR_LEN / 4; i += 256) {
        ((float4*)h0)[i] = hp0[i];
        ((float4*)h1)[i] = hp1[i];
    }
    const float* xb = x + batch * T_TOTAL;
    for (int j = t; j < 2080; j += 256) {
        const int xi = t0 - 1999 + j;
        xw[j] = (xi >= 0 && xi < T_TOTAL) ? xb[xi] : 0.0f;
    }
    __syncthreads();

    if (t < 250) {
        const int o0 = (t % 10) * 8;           // outputs o0..o0+7
        const int kb = (t / 10) * 80;          // taps kb..kb+79
        float s0[8] = {0,0,0,0,0,0,0,0}, s1[8] = {0,0,0,0,0,0,0,0};
        int B = 1996 + o0 - kb;                // mult of 4
        float4 w1 = ((const float4*)xw)[B / 4 + 1];
        float4 w2 = ((const float4*)xw)[B / 4 + 2];
        for (int s = 0; s < 20; s++) {
            const float4 w0 = ((const float4*)xw)[B / 4];
            const float4 ha = ((const float4*)h0)[kb / 4 + s];
            const float4 hb = ((const float4*)h1)[kb / 4 + s];
            const float wv[12] = {w0.x, w0.y, w0.z, w0.w,
                                  w1.x, w1.y, w1.z, w1.w,
                                  w2.x, w2.y, w2.z, w2.w};
            const float hav[4] = {ha.x, ha.y, ha.z, ha.w};
            const float hbv[4] = {hb.x, hb.y, hb.z, hb.w};
            #pragma unroll
            for (int jo = 0; jo < 8; jo++) {
                #pragma unroll
                for (int jk = 0; jk < 4; jk++) {
                    const float xv = wv[3 + jo - jk];
                    s0[jo] += hav[jk] * xv;
                    s1[jo] += hbv[jk] * xv;
                }
            }
            w2 = w1; w1 = w0; B -= 4;
        }
        const int rb = (t / 10) * 80 + o0;     // mult of 4
        *(float4*)&red0[rb]     = make_float4(s0[0], s0[1], s0[2], s0[3]);
        *(float4*)&red0[rb + 4] = make_float4(s0[4], s0[5], s0[6], s0[7]);
        *(float4*)&red1[rb]     = make_float4(s1[0], s1[1], s1[2], s1[3]);
        *(float4*)&red1[rb + 4] = make_float4(s1[4], s1[5], s1[6], s1[7]);
    }
    __syncthreads();

    if (t < PFRAME) {
        float S0 = 0.0f, S1 = 0.0f;
        #pragma unroll
        for (int kc = 0; kc < 25; kc++) {
            S0 += red0[kc * 80 + t];
            S1 += red1[kc * 80 + t];
        }
        const float w = (float)t * (1.0f / (float)PFRAME);
        y[batch * T_TOTAL + t0 + t] = (1.0f - w) * S0 + w * S1;
    }
}

extern "C" void kernel_launch(void* const* d_in, const int* in_sizes, int n_in,
                              void* d_out, int out_size, void* d_ws, size_t ws_size,
                              hipStream_t stream) {
    const float* x  = (const float*)d_in[0];   // (2, 24000)
    const float* mc = (const float*)d_in[1];   // (2, 300, 25)
    float* y = (float*)d_out;                  // (2, 24000)

    float2* E    = (float2*)d_ws;                                  // 9.84 MB
    float*  h_ws = (float*)((char*)d_ws + (size_t)NROWS * NHALF * sizeof(float2));

    const int nE = NROWS * NHALF;
    exp_spec_kernel<<<(nE + 255) / 256, 256, 0, stream>>>(mc, E);
    ifft_kernel<<<NROWS * 2, 256, 0, stream>>>(E, h_ws);
    fir_kernel<<<NROWS, 256, 0, stream>>>(x, h_ws, y);
}